// Round 4
// baseline (531.305 us; speedup 1.0000x reference)
//
#include <hip/hip_runtime.h>
#include <hip/hip_bf16.h>
#include <stdint.h>

// Problem: B=64, L=1024, V=1024, H=512, A=512
// out[0:65536)   = att_output [64][1024] fp32
// out[65536:...) = att_scores [64][1024] fp32

typedef __attribute__((ext_vector_type(8))) short bf16x8;
typedef __attribute__((ext_vector_type(8))) unsigned short ushortx8;
typedef __attribute__((ext_vector_type(4))) unsigned short ushortx4;
typedef __attribute__((ext_vector_type(4))) float f32x4;

#define LOG2E 1.4426950408889634f

__device__ __forceinline__ unsigned short f2bf(float f) {
  uint32_t u = __builtin_bit_cast(uint32_t, f);
  u += 0x7FFFu + ((u >> 16) & 1u);   // round-to-nearest-even
  return (unsigned short)(u >> 16);
}

__device__ __forceinline__ float fast_tanh(float x) {
  float e = __builtin_amdgcn_exp2f(x * 2.885390081777927f);  // 2*log2(e)
  return 1.0f - 2.0f * __builtin_amdgcn_rcpf(e + 1.0f);
}

__device__ __forceinline__ void load_lds16(const void* g, void* l) {
  __builtin_amdgcn_global_load_lds(
      (const __attribute__((address_space(1))) void*)g,
      (__attribute__((address_space(3))) void*)l, 16, 0, 0);
}

// ---------------------------------------------------------------------------
// K01: prep, grid 4608 x 256.
//  [0,4096):    convert vis fp32 -> visb bf16 in k2's staged chunk order.
//               visb slot (16B, 8 ushort) index = (blk*32 + t)*256 + kb*64 + row,
//               content = vis[blk*64+row][t*32 + kb*8 + j], j=0..7.
//               Each block: 16 rows x full K via LDS reorder (reads coalesced,
//               writes in 128B segments).
//  [4096,4352): pack W_enc -> Wst bf16, slot = t*2048 + kb*512 + a.
//  [4352,4608): zero att_output; dproj = dec@W_dec + b_dec + b_enc.
// ---------------------------------------------------------------------------
__global__ __launch_bounds__(256) void k01_prep(const float* __restrict__ vis,
                                                unsigned short* __restrict__ visb,
                                                const float* __restrict__ W,
                                                unsigned short* __restrict__ Wst,
                                                const float* __restrict__ dec,
                                                const float* __restrict__ Wd,
                                                const float* __restrict__ bd,
                                                const float* __restrict__ be,
                                                float* __restrict__ dproj,
                                                float* __restrict__ out) {
  __shared__ unsigned short S[16 * 1040];   // 32.5KB, row stride 1040 (bank-spread)
  const int tid = threadIdx.x;

  if (blockIdx.x < 4096) {
    const int c = blockIdx.x;                    // rows [c*16, +16)
    const size_t vbase = (size_t)c * 16 * 1024;
#pragma unroll
    for (int p = 0; p < 16; ++p) {
      f32x4 x = *(const f32x4*)(vis + vbase + p * 1024 + tid * 4);
      ushortx4 u;
      u[0] = f2bf(x[0]); u[1] = f2bf(x[1]); u[2] = f2bf(x[2]); u[3] = f2bf(x[3]);
      *(ushortx4*)(&S[p * 1040 + tid * 4]) = u;
    }
    __syncthreads();
    const int blk = c >> 2;            // 64-row block id
    const int rb = (c & 3) * 16;       // row base within block
    const int s = tid >> 1;            // segment 0..127
    const int h = tid & 1;
    const int t = s >> 2;
    const int kb = s & 3;
    unsigned short* dst =
        visb + (((size_t)blk * 32 + t) * 256 + kb * 64 + rb + h * 8) * 8;
    const unsigned short* srcS = &S[(h * 8) * 1040 + t * 32 + kb * 8];
#pragma unroll
    for (int r = 0; r < 8; ++r)
      *(ushortx8*)(dst + r * 8) = *(const ushortx8*)(srcS + r * 1040);
  } else if (blockIdx.x < 4352) {
    const int Sl = (blockIdx.x - 4096) * 256 + tid;  // 65536 slots
    const int t = Sl >> 11;
    const int kb = (Sl >> 9) & 3;
    const int a = Sl & 511;
    const int k0 = t * 32 + kb * 8;
    ushortx8 p;
#pragma unroll
    for (int j = 0; j < 8; ++j) p[j] = f2bf(W[(size_t)(k0 + j) * 512 + a]);
    *(ushortx8*)(Wst + (size_t)Sl * 8) = p;
  } else {
    const int q = blockIdx.x - 4352;  // 0..255
    out[q * 256 + tid] = 0.0f;        // zero att_output for k34's atomics
    const int b = q >> 2;
    const int a = (q & 3) * 128 + (tid & 127);
    const int hh = tid >> 7;
    const float* dr = dec + b * 512 + hh * 256;
    const float* wc = Wd + (size_t)(hh * 256) * 512 + a;
    float acc = 0.f;
#pragma unroll 8
    for (int h = 0; h < 256; ++h) acc = fmaf(dr[h], wc[(size_t)h * 512], acc);
    float* sh = (float*)S;
    if (hh == 1) sh[tid & 127] = acc;
    __syncthreads();
    if (hh == 0) dproj[b * 512 + a] = acc + sh[tid] + bd[a] + be[a];
  }
}

// ---------------------------------------------------------------------------
// K2: fused  logits[b,l] = sum_a w_full[a]*tanh( (visb@Wst)[b,l,a] + dproj[b,a] )
// 64M x 512N per block, 256 threads = 4 waves (wn = wave), wave tile 64x128.
// A: 1 global_load_lds 16B/thread from contiguous L3-hot visb chunk (4KB/iter),
//    LDS double-buffered (8KB total) -> 2 blocks/CU co-resident.
// B: 8 coalesced dwordx4/lane straight from L2-resident Wst into registers,
//    double-buffered in regs (static bA/bB naming, no dynamic indexing).
// ---------------------------------------------------------------------------
__global__ __launch_bounds__(256, 2) void k2_fused_gemm(
    const unsigned short* __restrict__ visb, const unsigned short* __restrict__ Wst,
    const float* __restrict__ dproj, const float* __restrict__ wfull,
    float* __restrict__ logits) {
  alignas(16) __shared__ unsigned short Al[2][2048];  // 256 slots x 8 ushort

  const int tid = threadIdx.x;
  const int lane = tid & 63;
  const int wn = tid >> 6;           // wave -> cols [wn*128, +128)
  const int blk = blockIdx.x;        // 0..1023, rows [blk*64, +64)
  const int b = blk >> 4;
  const size_t mbase = (size_t)blk * 64;

  // A: per-thread global src (wave-contiguous); per-wave uniform LDS base
  const unsigned short* agsrc = visb + ((size_t)blk * 32 * 256 + tid) * 8;
  // B: lane's fragment base slot = kb*512 + col  (8-ushort slots)
  const ushortx8* bbase = (const ushortx8*)Wst +
                          ((size_t)(lane >> 4) * 512 + wn * 128 + (lane & 15));

  f32x4 acc[4][8];
#pragma unroll
  for (int m = 0; m < 4; ++m)
#pragma unroll
    for (int n = 0; n < 8; ++n) acc[m][n] = (f32x4){0.f, 0.f, 0.f, 0.f};

  const int a_rd = (lane >> 4) * 512 + (lane & 15) * 8;  // ushort; + m*128

#define STAGEA(t, buf) load_lds16(agsrc + (size_t)(t) * 2048, &Al[buf][wn * 512])
#define LOADB(t, arr)                                                    \
  {                                                                      \
    const ushortx8* bp = bbase + (size_t)(t) * 2048;                     \
    _Pragma("unroll") for (int n = 0; n < 8; ++n)                        \
        arr[n] = *(const bf16x8*)(bp + n * 16);                          \
  }
#define COMPUTE(buf, arr)                                                \
  {                                                                      \
    bf16x8 af[4];                                                        \
    _Pragma("unroll") for (int m = 0; m < 4; ++m)                        \
        af[m] = *(const bf16x8*)(&Al[buf][a_rd + m * 128]);              \
    _Pragma("unroll") for (int m = 0; m < 4; ++m)                        \
        _Pragma("unroll") for (int n = 0; n < 8; ++n)                    \
            acc[m][n] = __builtin_amdgcn_mfma_f32_16x16x32_bf16(         \
                af[m], arr[n], acc[m][n], 0, 0, 0);                      \
  }

  bf16x8 bA[8], bB[8];
  STAGEA(0, 0);
  LOADB(0, bA);

  for (int tt = 0; tt < 32; tt += 2) {
    __syncthreads();                     // Al[0] + bA drained (issued 1 iter ago)
    if (tt < 31) { STAGEA(tt + 1, 1); LOADB(tt + 1, bB); }
    COMPUTE(0, bA);
    __syncthreads();                     // Al[1] + bB drained
    if (tt + 1 < 31) { STAGEA(tt + 2, 0); LOADB(tt + 2, bA); }
    COMPUTE(1, bB);
  }
#undef STAGEA
#undef LOADB
#undef COMPUTE

  // Epilogue: D[row = 16m + (lane>>4)*4 + r][col = wn*128 + 16n + (lane&15)]
  const float* dp = dproj + b * 512 + wn * 128 + (lane & 15);
  const float* wf = wfull + wn * 128 + (lane & 15);
  float dpv[8], wfv[8];
#pragma unroll
  for (int n = 0; n < 8; ++n) { dpv[n] = dp[n * 16]; wfv[n] = wf[n * 16]; }

  float* Lred = (float*)Al;   // [64 rows][4 wn] overlay (1KB)
  __syncthreads();

#pragma unroll
  for (int m = 0; m < 4; ++m) {
#pragma unroll
    for (int r = 0; r < 4; ++r) {
      float s = 0.f;
#pragma unroll
      for (int n = 0; n < 8; ++n)
        s += wfv[n] * fast_tanh(acc[m][n][r] + dpv[n]);
      s += __shfl_xor(s, 1, 64);
      s += __shfl_xor(s, 2, 64);
      s += __shfl_xor(s, 4, 64);
      s += __shfl_xor(s, 8, 64);
      if ((lane & 15) == 0) {
        int row = m * 16 + (lane >> 4) * 4 + r;
        Lred[row * 4 + wn] = s;
      }
    }
  }
  __syncthreads();
  if (tid < 64) {
    f32x4 v = *(const f32x4*)(&Lred[tid * 4]);
    logits[mbase + tid] = v[0] + v[1] + v[2] + v[3];
  }
}

// ---------------------------------------------------------------------------
// K34: fused softmax + weighted sum. grid (64 b, 8 chunks of 128 l).
// ---------------------------------------------------------------------------
__global__ __launch_bounds__(256) void k34_attout(const float* __restrict__ logits,
                                                  const float* __restrict__ vis,
                                                  float* __restrict__ out) {
  const int b = blockIdx.x;
  const int chunk = blockIdx.y;
  const int tid = threadIdx.x;
  const int wid = tid >> 6;
  const int lane = tid & 63;
  const float* base = logits + b * 1024;

  float x[4];
#pragma unroll
  for (int j = 0; j < 4; ++j) x[j] = base[j * 256 + tid];
  float mx = fmaxf(fmaxf(x[0], x[1]), fmaxf(x[2], x[3]));
#pragma unroll
  for (int d = 1; d < 64; d <<= 1) mx = fmaxf(mx, __shfl_xor(mx, d, 64));
  __shared__ float redm[4], reds[4];
  if (lane == 0) redm[wid] = mx;
  __syncthreads();
  mx = fmaxf(fmaxf(redm[0], redm[1]), fmaxf(redm[2], redm[3]));
  float s = 0.f;
#pragma unroll
  for (int j = 0; j < 4; ++j) s += __builtin_amdgcn_exp2f((x[j] - mx) * LOG2E);
#pragma unroll
  for (int d = 1; d < 64; d <<= 1) s += __shfl_xor(s, d, 64);
  if (lane == 0) reds[wid] = s;
  __syncthreads();
  s = reds[0] + reds[1] + reds[2] + reds[3];
  const float inv = 1.0f / s;

  if (chunk == 0) {
#pragma unroll
    for (int j = 0; j < 4; ++j)
      out[65536 + b * 1024 + j * 256 + tid] =
          __builtin_amdgcn_exp2f((x[j] - mx) * LOG2E) * inv;
  }

  __shared__ float p[128];
  const int l0 = chunk * 128;
  if (tid < 128)
    p[tid] = __builtin_amdgcn_exp2f((base[l0 + tid] - mx) * LOG2E) * inv;
  __syncthreads();

  const f32x4* vb = (const f32x4*)(vis + ((size_t)b * 1024 + (size_t)l0) * 1024) + tid;
  f32x4 acc0 = (f32x4){0.f, 0.f, 0.f, 0.f};
  f32x4 acc1 = (f32x4){0.f, 0.f, 0.f, 0.f};
#pragma unroll 4
  for (int l = 0; l < 128; l += 2) {
    acc0 += vb[(size_t)l * 256] * p[l];
    acc1 += vb[(size_t)(l + 1) * 256] * p[l + 1];
  }
  f32x4 acc = acc0 + acc1;
  float* o = out + b * 1024 + tid * 4;
  atomicAdd(o + 0, acc[0]);
  atomicAdd(o + 1, acc[1]);
  atomicAdd(o + 2, acc[2]);
  atomicAdd(o + 3, acc[3]);
}

extern "C" void kernel_launch(void* const* d_in, const int* in_sizes, int n_in,
                              void* d_out, int out_size, void* d_ws, size_t ws_size,
                              hipStream_t stream) {
  const float* vis = (const float*)d_in[0];
  const float* dec = (const float*)d_in[1];
  const float* Wenc = (const float*)d_in[2];
  const float* benc = (const float*)d_in[3];
  const float* Wdec = (const float*)d_in[4];
  const float* bdec = (const float*)d_in[5];
  const float* wfull = (const float*)d_in[6];
  // d_in[7] = b_full: softmax-shift-invariant -> unused.
  float* out = (float*)d_out;
  char* ws = (char*)d_ws;
  unsigned short* Wst = (unsigned short*)ws;               // 1 MB
  float* dproj = (float*)(ws + (1 << 20));                 // 128 KB
  float* logits = (float*)(ws + (1 << 20) + (128 << 10));  // 256 KB
  unsigned short* visb = (unsigned short*)(ws + (2 << 20));  // 128 MiB bf16 staged vis

  hipLaunchKernelGGL(k01_prep, dim3(4608), dim3(256), 0, stream,
                     vis, visb, Wenc, Wst, dec, Wdec, bdec, benc, dproj, out);
  hipLaunchKernelGGL(k2_fused_gemm, dim3(1024), dim3(256), 0, stream,
                     visb, Wst, dproj, wfull, logits);
  hipLaunchKernelGGL(k34_attout, dim3(64, 8), dim3(256), 0, stream,
                     logits, vis, out);
}